// Round 3
// baseline (663.377 us; speedup 1.0000x reference)
//
#include <hip/hip_runtime.h>

typedef __attribute__((ext_vector_type(8))) short bf16x8;
typedef __attribute__((ext_vector_type(4))) float f32x4;
typedef __attribute__((ext_vector_type(4))) unsigned short us4;

static __device__ __forceinline__ float bf2f(unsigned short u) {
    union { unsigned int i; float f; } cv; cv.i = ((unsigned int)u) << 16;
    return cv.f;
}
static __device__ __forceinline__ unsigned short f2bf(float f) {
    union { float f; unsigned int i; } cv; cv.f = f;
    unsigned int x = cv.i;
    unsigned int lsb = (x >> 16) & 1u;
    x += 0x7fffu + lsb;
    return (unsigned short)(x >> 16);
}

// async global->LDS, 16B per lane; LDS dest is wave-uniform base + lane*16
static __device__ __forceinline__ void gload16(const void* g, void* l) {
    __builtin_amdgcn_global_load_lds(
        (const __attribute__((address_space(1))) void*)g,
        (__attribute__((address_space(3))) void*)l, 16, 0, 0);
}

// ---------------- CSR build ----------------
__global__ __launch_bounds__(256) void k_hist(const int* __restrict__ dst,
                                              int* __restrict__ cnt, int E) {
    int i = blockIdx.x * 256 + threadIdx.x;
    if (i < E) atomicAdd(&cnt[dst[i]], 1);
}

__global__ __launch_bounds__(256) void k_bsum(const int* __restrict__ cnt,
                                              int* __restrict__ bsum, int M) {
    __shared__ int sm[256];
    int t = threadIdx.x;
    int base = blockIdx.x * 1024 + t * 4;
    int s = 0;
#pragma unroll
    for (int j = 0; j < 4; ++j) {
        int i = base + j;
        if (i < M) s += cnt[i];
    }
    sm[t] = s;
    __syncthreads();
    for (int off = 128; off; off >>= 1) {
        if (t < off) sm[t] += sm[t + off];
        __syncthreads();
    }
    if (t == 0) bsum[blockIdx.x] = sm[0];
}

__global__ void k_scanb(int* __restrict__ bsum, int NB,
                        int* __restrict__ rowptr, int M, int E) {
    if (threadIdx.x == 0 && blockIdx.x == 0) {
        int run = 0;
        for (int b = 0; b < NB; ++b) {
            int v = bsum[b];
            bsum[b] = run;
            run += v;
        }
        rowptr[M] = E;
    }
}

__global__ __launch_bounds__(256) void k_rowptr(const int* __restrict__ cnt,
                                                const int* __restrict__ bsum,
                                                int* __restrict__ rowptr,
                                                int* __restrict__ cursor, int M) {
    __shared__ int sm[256];
    int t = threadIdx.x;
    int base = blockIdx.x * 1024 + t * 4;
    int c[4];
    int ts = 0;
#pragma unroll
    for (int j = 0; j < 4; ++j) {
        int i = base + j;
        c[j] = (i < M) ? cnt[i] : 0;
        ts += c[j];
    }
    sm[t] = ts;
    __syncthreads();
    for (int off = 1; off < 256; off <<= 1) {
        int v = (t >= off) ? sm[t - off] : 0;
        __syncthreads();
        sm[t] += v;
        __syncthreads();
    }
    int ex = bsum[blockIdx.x] + sm[t] - ts;
#pragma unroll
    for (int j = 0; j < 4; ++j) {
        int i = base + j;
        if (i < M) {
            rowptr[i] = ex;
            cursor[i] = ex;
        }
        ex += c[j];
    }
}

__global__ __launch_bounds__(256) void k_place(const int* __restrict__ src,
                                               const int* __restrict__ dst,
                                               int* __restrict__ cursor,
                                               int* __restrict__ eidx, int E) {
    int i = blockIdx.x * 256 + threadIdx.x;
    if (i < E) {
        int slot = atomicAdd(&cursor[dst[i]], 1);
        eidx[slot] = src[i];
    }
}

// ---------------- f32 -> bf16 bulk convert ----------------
__global__ __launch_bounds__(256) void k_convx(const float* __restrict__ x,
                                               unsigned short* __restrict__ xb, int n8) {
    int i = blockIdx.x * 256 + threadIdx.x;
    if (i >= n8) return;
    const f32x4* p = (const f32x4*)(x + (size_t)i * 8);
    f32x4 u0 = p[0], u1 = p[1];
    union { bf16x8 v; unsigned short u[8]; } tmp;
    tmp.u[0] = f2bf(u0.x); tmp.u[1] = f2bf(u0.y);
    tmp.u[2] = f2bf(u0.z); tmp.u[3] = f2bf(u0.w);
    tmp.u[4] = f2bf(u1.x); tmp.u[5] = f2bf(u1.y);
    tmp.u[6] = f2bf(u1.z); tmp.u[7] = f2bf(u1.w);
    *(bf16x8*)(xb + (size_t)i * 8) = tmp.v;
}

// ---------------- pull aggregation: mean over neighbors ----------------
__global__ __launch_bounds__(256) void k_gather_mean(const unsigned short* __restrict__ xsrc,
                                                     const int* __restrict__ rowptr,
                                                     const int* __restrict__ eidx,
                                                     unsigned short* __restrict__ mean, int M) {
    int r = blockIdx.x * 4 + (threadIdx.x >> 6);
    if (r >= M) return;
    int l = threadIdx.x & 63;
    int s0 = rowptr[r], s1 = rowptr[r + 1];
    float a0 = 0.f, a1 = 0.f, a2 = 0.f, a3 = 0.f;
    for (int e = s0; e < s1; ++e) {
        int s = eidx[e];
        us4 v = *((const us4*)(xsrc + (size_t)s * 256) + l);
        a0 += bf2f(v.x); a1 += bf2f(v.y); a2 += bf2f(v.z); a3 += bf2f(v.w);
    }
    float rinv = (s1 > s0) ? 1.0f / (float)(s1 - s0) : 0.0f;
    us4 o;
    o.x = f2bf(a0 * rinv); o.y = f2bf(a1 * rinv);
    o.z = f2bf(a2 * rinv); o.w = f2bf(a3 * rinv);
    *((us4*)(mean + (size_t)r * 256) + l) = o;
}

// ---------------- weight conversion ----------------
__global__ __launch_bounds__(256) void k_convw(const float* __restrict__ Wl,
                                               const float* __restrict__ Wr,
                                               const float* __restrict__ fcW,
                                               unsigned short* __restrict__ Wc1,
                                               unsigned short* __restrict__ Wc2,
                                               unsigned short* __restrict__ fcWb) {
    int idx = blockIdx.x * 256 + threadIdx.x;
    if (idx < 2 * 256 * 512) {
        int layer = idx >> 17;
        int r = idx & ((1 << 17) - 1);
        int n = r >> 9;
        int k = r & 511;
        int base = layer * 3 * 256 * 256;
        float v = (k < 256) ? Wl[base + n * 256 + k] : Wr[base + n * 256 + (k - 256)];
        (layer ? Wc2 : Wc1)[n * 512 + k] = f2bf(v);
    } else {
        int i = idx - 2 * 256 * 512;
        if (i < 128 * 256) fcWb[i] = f2bf(fcW[i]);
    }
}

// ---------------- layer GEMM: out = relu([mean | xs] @ Wc^T + bias), bf16 out ----------------
// BM=128, BN=256(full), K=512, BK=32. 512 threads = 8 waves (2 Mx4 N), per-wave 64x64.
// LDS in fragment-major subtiles (16 rows x 32 k = 1KB): gload_lds write and
// ds_read_b128 (base + lane*16) are both linear -> zero bank conflicts.
__global__ __launch_bounds__(512, 4) void k_sage_gemm(const unsigned short* __restrict__ meanb,
                                                      const unsigned short* __restrict__ xs,
                                                      const unsigned short* __restrict__ Wc,
                                                      const float* __restrict__ bias,
                                                      unsigned short* __restrict__ out, int M) {
    __shared__ __align__(16) unsigned short Asm[8 * 512];   // 128 rows x 32 k
    __shared__ __align__(16) unsigned short Bsm[16 * 512];  // 256 n   x 32 k
    const int t = threadIdx.x;
    const int w = t >> 6, l = t & 63;
    const int wr = w >> 2, wc = w & 3;
    const int row0 = blockIdx.x * 128;

    f32x4 acc[4][4];
#pragma unroll
    for (int m = 0; m < 4; ++m)
#pragma unroll
        for (int n = 0; n < 4; ++n)
#pragma unroll
            for (int j = 0; j < 4; ++j) acc[m][n][j] = 0.0f;

    // staging: thread t stages chunk (row = w*16 + (l&15), kslot = l>>4)
    const int lrow = l & 15;
    const int slot = l >> 4;                       // k elem offset slot*8
    int a_row = row0 + (w << 4) + lrow;
    if (a_row > M - 1) a_row = M - 1;
    const size_t a_off = (size_t)a_row * 256 + slot * 8;
    const int b_n0 = (w << 4) + lrow;              // subtile w
    const int b_n1 = 128 + (w << 4) + lrow;        // subtile 8+w
    unsigned short* a_dst = &Asm[w * 512];
    unsigned short* b_dst0 = &Bsm[w * 512];
    unsigned short* b_dst1 = &Bsm[(8 + w) * 512];

    for (int k0 = 0; k0 < 512; k0 += 32) {
        const unsigned short* asrc = (k0 < 256) ? (meanb + a_off + k0)
                                                : (xs + a_off + (k0 - 256));
        gload16(asrc, a_dst);
        gload16(Wc + b_n0 * 512 + k0 + slot * 8, b_dst0);
        gload16(Wc + b_n1 * 512 + k0 + slot * 8, b_dst1);
        __syncthreads();
        bf16x8 a[4];
#pragma unroll
        for (int m = 0; m < 4; ++m)
            a[m] = *(const bf16x8*)(&Asm[(wr * 4 + m) * 512 + l * 8]);
#pragma unroll
        for (int n = 0; n < 4; ++n) {
            bf16x8 b = *(const bf16x8*)(&Bsm[(wc * 4 + n) * 512 + l * 8]);
#pragma unroll
            for (int m = 0; m < 4; ++m)
                acc[m][n] = __builtin_amdgcn_mfma_f32_16x16x32_bf16(a[m], b, acc[m][n], 0, 0, 0);
        }
        __syncthreads();
    }

    // epilogue: D mapping col=lane&15 (from B row n), row=(lane>>4)*4+reg (from A row)
#pragma unroll
    for (int n = 0; n < 4; ++n) {
        int col = (wc << 6) + (n << 4) + lrow;
        float bb = bias[col];
#pragma unroll
        for (int m = 0; m < 4; ++m) {
#pragma unroll
            for (int r = 0; r < 4; ++r) {
                int grow = row0 + (wr << 6) + (m << 4) + slot * 4 + r;
                if (grow < M) {
                    float v = acc[m][n][r] + bb;
                    out[(size_t)grow * 256 + col] = f2bf(fmaxf(v, 0.0f));
                }
            }
        }
    }
}

// ---------------- fc GEMM: out = g @ fcW^T + fcb, fp32 out; g aliases d_out ----------------
// BM=128, BN=128(full), K=256, BK=32. 512 threads, per-wave 64x32.
__global__ __launch_bounds__(512, 4) void k_fc_gemm(const unsigned short* __restrict__ g,
                                                    const unsigned short* __restrict__ fcWb,
                                                    const float* __restrict__ fcb,
                                                    float* __restrict__ out, int M) {
    __shared__ __align__(16) unsigned short Asm[8 * 512];  // 128 rows x 32 k
    __shared__ __align__(16) unsigned short Bsm[8 * 512];  // 128 n    x 32 k
    const int t = threadIdx.x;
    const int w = t >> 6, l = t & 63;
    const int wr = w >> 2, wc = w & 3;
    const int row0 = blockIdx.x * 128;

    f32x4 acc[4][2];
#pragma unroll
    for (int m = 0; m < 4; ++m)
#pragma unroll
        for (int n = 0; n < 2; ++n)
#pragma unroll
            for (int j = 0; j < 4; ++j) acc[m][n][j] = 0.0f;

    const int lrow = l & 15;
    const int slot = l >> 4;
    int a_row = row0 + (w << 4) + lrow;
    if (a_row > M - 1) a_row = M - 1;
    const size_t a_off = (size_t)a_row * 256 + slot * 8;
    const int b_n = (w << 4) + lrow;               // subtile w (n = 0..127)
    unsigned short* a_dst = &Asm[w * 512];
    unsigned short* b_dst = &Bsm[w * 512];

    for (int k0 = 0; k0 < 256; k0 += 32) {
        gload16(g + a_off + k0, a_dst);
        gload16(fcWb + b_n * 256 + k0 + slot * 8, b_dst);
        __syncthreads();
        bf16x8 a[4];
#pragma unroll
        for (int m = 0; m < 4; ++m)
            a[m] = *(const bf16x8*)(&Asm[(wr * 4 + m) * 512 + l * 8]);
#pragma unroll
        for (int n = 0; n < 2; ++n) {
            bf16x8 b = *(const bf16x8*)(&Bsm[(wc * 2 + n) * 512 + l * 8]);
#pragma unroll
            for (int m = 0; m < 4; ++m)
                acc[m][n] = __builtin_amdgcn_mfma_f32_16x16x32_bf16(a[m], b, acc[m][n], 0, 0, 0);
        }
        __syncthreads();
    }

#pragma unroll
    for (int n = 0; n < 2; ++n) {
        int col = (wc << 5) + (n << 4) + lrow;
        float bb = fcb[col];
#pragma unroll
        for (int m = 0; m < 4; ++m) {
#pragma unroll
            for (int r = 0; r < 4; ++r) {
                int grow = row0 + (wr << 6) + (m << 4) + slot * 4 + r;
                if (grow < M) out[(size_t)grow * 128 + col] = acc[m][n][r] + bb;
            }
        }
    }
}

extern "C" void kernel_launch(void* const* d_in, const int* in_sizes, int n_in,
                              void* d_out, int out_size, void* d_ws, size_t ws_size,
                              hipStream_t stream) {
    const float* x_word = (const float*)d_in[0];
    const float* Wl  = (const float*)d_in[3];
    const float* bl  = (const float*)d_in[4];
    const float* Wr  = (const float*)d_in[5];
    const float* fcW = (const float*)d_in[6];
    const float* fcb = (const float*)d_in[7];
    const int* src = (const int*)d_in[8];
    const int* dst = (const int*)d_in[9];

    const int M = in_sizes[0] / 256;   // 200000
    const int E = in_sizes[8];         // 400000
    const int NB = (M + 1023) / 1024;

    char* ws = (char*)d_ws;
    size_t off = 0;
    auto alloc = [&](size_t bytes) {
        void* p = ws + off;
        off = (off + bytes + 255) & ~(size_t)255;
        return p;
    };
    int* cnt_i  = (int*)alloc((size_t)M * 4);
    int* rowptr = (int*)alloc((size_t)(M + 1) * 4);
    int* cursor = (int*)alloc((size_t)M * 4);
    int* eidx   = (int*)alloc((size_t)E * 4);
    int* bsum   = (int*)alloc((size_t)NB * 4);
    unsigned short* xb    = (unsigned short*)alloc((size_t)M * 256 * 2);
    unsigned short* meanb = (unsigned short*)alloc((size_t)M * 256 * 2);
    unsigned short* h     = (unsigned short*)alloc((size_t)M * 256 * 2);
    unsigned short* Wc1   = (unsigned short*)alloc(256 * 512 * 2);
    unsigned short* Wc2   = (unsigned short*)alloc(256 * 512 * 2);
    unsigned short* fcWb  = (unsigned short*)alloc(128 * 256 * 2);

    unsigned short* g = (unsigned short*)d_out;  // bf16 g staged inside d_out

    // CSR build
    hipMemsetAsync(cnt_i, 0, (size_t)M * 4, stream);
    k_hist<<<(E + 255) / 256, 256, 0, stream>>>(dst, cnt_i, E);
    k_bsum<<<NB, 256, 0, stream>>>(cnt_i, bsum, M);
    k_scanb<<<1, 64, 0, stream>>>(bsum, NB, rowptr, M, E);
    k_rowptr<<<NB, 256, 0, stream>>>(cnt_i, bsum, rowptr, cursor, M);
    k_place<<<(E + 255) / 256, 256, 0, stream>>>(src, dst, cursor, eidx, E);

    // weights + x -> bf16
    k_convw<<<1152, 256, 0, stream>>>(Wl, Wr, fcW, Wc1, Wc2, fcWb);
    k_convx<<<(M * 256 / 8 + 255) / 256, 256, 0, stream>>>(x_word, xb, M * 256 / 8);

    const int GB = (M + 127) / 128;

    // Layer 1
    k_gather_mean<<<(M + 3) / 4, 256, 0, stream>>>(xb, rowptr, eidx, meanb, M);
    k_sage_gemm<<<GB, 512, 0, stream>>>(meanb, xb, Wc1, bl, h, M);

    // Layer 2
    k_gather_mean<<<(M + 3) / 4, 256, 0, stream>>>(h, rowptr, eidx, meanb, M);
    k_sage_gemm<<<GB, 512, 0, stream>>>(meanb, h, Wc2, bl + 3 * 256, g, M);

    // fc head
    k_fc_gemm<<<GB, 512, 0, stream>>>(g, fcWb, fcb, (float*)d_out, M);
}

// Round 4
// 649.552 us; speedup vs baseline: 1.0213x; 1.0213x over previous
//
#include <hip/hip_runtime.h>

typedef __attribute__((ext_vector_type(8))) short bf16x8;
typedef __attribute__((ext_vector_type(4))) float f32x4;
typedef __attribute__((ext_vector_type(4))) unsigned short us4;

static __device__ __forceinline__ float bf2f(unsigned short u) {
    union { unsigned int i; float f; } cv; cv.i = ((unsigned int)u) << 16;
    return cv.f;
}
static __device__ __forceinline__ unsigned short f2bf(float f) {
    union { float f; unsigned int i; } cv; cv.f = f;
    unsigned int x = cv.i;
    unsigned int lsb = (x >> 16) & 1u;
    x += 0x7fffu + lsb;
    return (unsigned short)(x >> 16);
}

// async global->LDS, 16B per lane; LDS dest is wave-uniform base + lane*16
static __device__ __forceinline__ void gload16(const void* g, void* l) {
    __builtin_amdgcn_global_load_lds(
        (const __attribute__((address_space(1))) void*)g,
        (__attribute__((address_space(3))) void*)l, 16, 0, 0);
}

// ---------------- CSR build ----------------
__global__ __launch_bounds__(256) void k_hist(const int* __restrict__ dst,
                                              int* __restrict__ cnt, int E) {
    int i = blockIdx.x * 256 + threadIdx.x;
    if (i < E) atomicAdd(&cnt[dst[i]], 1);
}

__global__ __launch_bounds__(256) void k_bsum(const int* __restrict__ cnt,
                                              int* __restrict__ bsum, int M) {
    __shared__ int sm[256];
    int t = threadIdx.x;
    int base = blockIdx.x * 1024 + t * 4;
    int s = 0;
#pragma unroll
    for (int j = 0; j < 4; ++j) {
        int i = base + j;
        if (i < M) s += cnt[i];
    }
    sm[t] = s;
    __syncthreads();
    for (int off = 128; off; off >>= 1) {
        if (t < off) sm[t] += sm[t + off];
        __syncthreads();
    }
    if (t == 0) bsum[blockIdx.x] = sm[0];
}

__global__ void k_scanb(int* __restrict__ bsum, int NB,
                        int* __restrict__ rowptr, int M, int E) {
    if (threadIdx.x == 0 && blockIdx.x == 0) {
        int run = 0;
        for (int b = 0; b < NB; ++b) {
            int v = bsum[b];
            bsum[b] = run;
            run += v;
        }
        rowptr[M] = E;
    }
}

__global__ __launch_bounds__(256) void k_rowptr(const int* __restrict__ cnt,
                                                const int* __restrict__ bsum,
                                                int* __restrict__ rowptr,
                                                int* __restrict__ cursor, int M) {
    __shared__ int sm[256];
    int t = threadIdx.x;
    int base = blockIdx.x * 1024 + t * 4;
    int c[4];
    int ts = 0;
#pragma unroll
    for (int j = 0; j < 4; ++j) {
        int i = base + j;
        c[j] = (i < M) ? cnt[i] : 0;
        ts += c[j];
    }
    sm[t] = ts;
    __syncthreads();
    for (int off = 1; off < 256; off <<= 1) {
        int v = (t >= off) ? sm[t - off] : 0;
        __syncthreads();
        sm[t] += v;
        __syncthreads();
    }
    int ex = bsum[blockIdx.x] + sm[t] - ts;
#pragma unroll
    for (int j = 0; j < 4; ++j) {
        int i = base + j;
        if (i < M) {
            rowptr[i] = ex;
            cursor[i] = ex;
        }
        ex += c[j];
    }
}

__global__ __launch_bounds__(256) void k_place(const int* __restrict__ src,
                                               const int* __restrict__ dst,
                                               int* __restrict__ cursor,
                                               int* __restrict__ eidx, int E) {
    int i = blockIdx.x * 256 + threadIdx.x;
    if (i < E) {
        int slot = atomicAdd(&cursor[dst[i]], 1);
        eidx[slot] = src[i];
    }
}

// ---------------- f32 -> bf16 bulk convert ----------------
__global__ __launch_bounds__(256) void k_convx(const float* __restrict__ x,
                                               unsigned short* __restrict__ xb, int n8) {
    int i = blockIdx.x * 256 + threadIdx.x;
    if (i >= n8) return;
    const f32x4* p = (const f32x4*)(x + (size_t)i * 8);
    f32x4 u0 = p[0], u1 = p[1];
    union { bf16x8 v; unsigned short u[8]; } tmp;
    tmp.u[0] = f2bf(u0.x); tmp.u[1] = f2bf(u0.y);
    tmp.u[2] = f2bf(u0.z); tmp.u[3] = f2bf(u0.w);
    tmp.u[4] = f2bf(u1.x); tmp.u[5] = f2bf(u1.y);
    tmp.u[6] = f2bf(u1.z); tmp.u[7] = f2bf(u1.w);
    *(bf16x8*)(xb + (size_t)i * 8) = tmp.v;
}

// ---------------- pull aggregation: mean over neighbors (2-way MLP unroll) ----------------
__global__ __launch_bounds__(256) void k_gather_mean(const unsigned short* __restrict__ xsrc,
                                                     const int* __restrict__ rowptr,
                                                     const int* __restrict__ eidx,
                                                     unsigned short* __restrict__ mean, int M) {
    int r = blockIdx.x * 4 + (threadIdx.x >> 6);
    if (r >= M) return;
    int l = threadIdx.x & 63;
    int s0 = rowptr[r], s1 = rowptr[r + 1];
    float a0 = 0.f, a1 = 0.f, a2 = 0.f, a3 = 0.f;
    int e = s0;
    for (; e + 2 <= s1; e += 2) {
        int sA = eidx[e], sB = eidx[e + 1];
        us4 vA = *((const us4*)(xsrc + (size_t)sA * 256) + l);
        us4 vB = *((const us4*)(xsrc + (size_t)sB * 256) + l);
        a0 += bf2f(vA.x) + bf2f(vB.x);
        a1 += bf2f(vA.y) + bf2f(vB.y);
        a2 += bf2f(vA.z) + bf2f(vB.z);
        a3 += bf2f(vA.w) + bf2f(vB.w);
    }
    if (e < s1) {
        int sA = eidx[e];
        us4 vA = *((const us4*)(xsrc + (size_t)sA * 256) + l);
        a0 += bf2f(vA.x); a1 += bf2f(vA.y); a2 += bf2f(vA.z); a3 += bf2f(vA.w);
    }
    float rinv = (s1 > s0) ? 1.0f / (float)(s1 - s0) : 0.0f;
    us4 o;
    o.x = f2bf(a0 * rinv); o.y = f2bf(a1 * rinv);
    o.z = f2bf(a2 * rinv); o.w = f2bf(a3 * rinv);
    *((us4*)(mean + (size_t)r * 256) + l) = o;
}

// ---------------- weight conversion ----------------
__global__ __launch_bounds__(256) void k_convw(const float* __restrict__ Wl,
                                               const float* __restrict__ Wr,
                                               const float* __restrict__ fcW,
                                               unsigned short* __restrict__ Wc1,
                                               unsigned short* __restrict__ Wc2,
                                               unsigned short* __restrict__ fcWb) {
    int idx = blockIdx.x * 256 + threadIdx.x;
    if (idx < 2 * 256 * 512) {
        int layer = idx >> 17;
        int r = idx & ((1 << 17) - 1);
        int n = r >> 9;
        int k = r & 511;
        int base = layer * 3 * 256 * 256;
        float v = (k < 256) ? Wl[base + n * 256 + k] : Wr[base + n * 256 + (k - 256)];
        (layer ? Wc2 : Wc1)[n * 512 + k] = f2bf(v);
    } else {
        int i = idx - 2 * 256 * 512;
        if (i < 128 * 256) fcWb[i] = f2bf(fcW[i]);
    }
}

// ---------------- layer GEMM: out = relu([mean | xs] @ Wc^T + bias), bf16 out ----------------
// BM=64, BN=256(full), K=512, BK=32. 256 threads = 4 waves; per-wave 64 rows x 64 cols.
// 2-phase double-buffered pipeline: stage(s+1) issued before compute(s); one barrier/step.
// Weights are the MFMA A-operand so each lane holds 4 consecutive out cols -> us4 stores.
__global__ __launch_bounds__(256, 4) void k_sage_gemm(const unsigned short* __restrict__ meanb,
                                                      const unsigned short* __restrict__ xs,
                                                      const unsigned short* __restrict__ Wc,
                                                      const float* __restrict__ bias,
                                                      unsigned short* __restrict__ out, int M) {
    __shared__ __align__(16) unsigned short Asm[2][2048];   // 64 rows x 32 k (frag-major subtiles)
    __shared__ __align__(16) unsigned short Bsm[2][8192];   // 256 n  x 32 k
    const int t = threadIdx.x;
    const int w = t >> 6, l = t & 63;
    const int lrow = l & 15, slot = l >> 4;
    const int row0 = blockIdx.x * 64;

    int a_row = row0 + w * 16 + lrow;
    if (a_row > M - 1) a_row = M - 1;
    const size_t a_base = (size_t)a_row * 256 + slot * 8;

    f32x4 acc[4][4];  // [act-row frag n][col frag m]
#pragma unroll
    for (int n = 0; n < 4; ++n)
#pragma unroll
        for (int m = 0; m < 4; ++m)
#pragma unroll
            for (int j = 0; j < 4; ++j) acc[n][m][j] = 0.0f;

    auto stage = [&](int bb, int k0) {
        const unsigned short* asrc = (k0 < 256) ? meanb + a_base + k0
                                                : xs + a_base + (k0 - 256);
        gload16(asrc, &Asm[bb][w * 512]);
#pragma unroll
        for (int i = 0; i < 4; ++i) {
            const int sb = w + 4 * i;
            gload16(Wc + (size_t)(sb * 16 + lrow) * 512 + k0 + slot * 8, &Bsm[bb][sb * 512]);
        }
    };

    stage(0, 0);
    __syncthreads();
    for (int s = 0; s < 16; ++s) {
        const int cur = s & 1;
        if (s < 15) stage(cur ^ 1, (s + 1) * 32);
        bf16x8 af[4], bf[4];
#pragma unroll
        for (int n = 0; n < 4; ++n)
            af[n] = *(const bf16x8*)(&Asm[cur][n * 512 + l * 8]);
#pragma unroll
        for (int m = 0; m < 4; ++m)
            bf[m] = *(const bf16x8*)(&Bsm[cur][(w * 4 + m) * 512 + l * 8]);
#pragma unroll
        for (int n = 0; n < 4; ++n)
#pragma unroll
            for (int m = 0; m < 4; ++m)
                acc[n][m] = __builtin_amdgcn_mfma_f32_16x16x32_bf16(bf[m], af[n], acc[n][m], 0, 0, 0);
        __syncthreads();
    }

    // epilogue: lane holds out[row0 + n*16 + lrow][w*64 + m*16 + slot*4 + (0..3)]
#pragma unroll
    for (int n = 0; n < 4; ++n) {
        const int grow = row0 + n * 16 + lrow;
        if (grow >= M) continue;
#pragma unroll
        for (int m = 0; m < 4; ++m) {
            const int gcol = w * 64 + m * 16 + slot * 4;
            f32x4 bv = *(const f32x4*)(bias + gcol);
            us4 o;
            o.x = f2bf(fmaxf(acc[n][m][0] + bv.x, 0.f));
            o.y = f2bf(fmaxf(acc[n][m][1] + bv.y, 0.f));
            o.z = f2bf(fmaxf(acc[n][m][2] + bv.z, 0.f));
            o.w = f2bf(fmaxf(acc[n][m][3] + bv.w, 0.f));
            *(us4*)(out + (size_t)grow * 256 + gcol) = o;
        }
    }
}

// ---------------- fc GEMM: out = g @ fcW^T + fcb, fp32 out; g aliases d_out ----------------
// BM=64, BN=128(full), K=256, BK=32. Same pipelined structure; f32x4 fully coalesced stores.
__global__ __launch_bounds__(256, 4) void k_fc_gemm(const unsigned short* __restrict__ g,
                                                    const unsigned short* __restrict__ fcWb,
                                                    const float* __restrict__ fcb,
                                                    float* __restrict__ out, int M) {
    __shared__ __align__(16) unsigned short Asm[2][2048];   // 64 rows x 32 k
    __shared__ __align__(16) unsigned short Bsm[2][4096];   // 128 n  x 32 k
    const int t = threadIdx.x;
    const int w = t >> 6, l = t & 63;
    const int lrow = l & 15, slot = l >> 4;
    const int row0 = blockIdx.x * 64;

    int a_row = row0 + w * 16 + lrow;
    if (a_row > M - 1) a_row = M - 1;
    const size_t a_base = (size_t)a_row * 256 + slot * 8;

    f32x4 acc[4][2];
#pragma unroll
    for (int n = 0; n < 4; ++n)
#pragma unroll
        for (int m = 0; m < 2; ++m)
#pragma unroll
            for (int j = 0; j < 4; ++j) acc[n][m][j] = 0.0f;

    auto stage = [&](int bb, int k0) {
        gload16(g + a_base + k0, &Asm[bb][w * 512]);
#pragma unroll
        for (int i = 0; i < 2; ++i) {
            const int sb = w + 4 * i;
            gload16(fcWb + (size_t)(sb * 16 + lrow) * 256 + k0 + slot * 8, &Bsm[bb][sb * 512]);
        }
    };

    stage(0, 0);
    __syncthreads();
    for (int s = 0; s < 8; ++s) {
        const int cur = s & 1;
        if (s < 7) stage(cur ^ 1, (s + 1) * 32);
        bf16x8 af[4], bf[2];
#pragma unroll
        for (int n = 0; n < 4; ++n)
            af[n] = *(const bf16x8*)(&Asm[cur][n * 512 + l * 8]);
#pragma unroll
        for (int m = 0; m < 2; ++m)
            bf[m] = *(const bf16x8*)(&Bsm[cur][(w * 2 + m) * 512 + l * 8]);
#pragma unroll
        for (int n = 0; n < 4; ++n)
#pragma unroll
            for (int m = 0; m < 2; ++m)
                acc[n][m] = __builtin_amdgcn_mfma_f32_16x16x32_bf16(bf[m], af[n], acc[n][m], 0, 0, 0);
        __syncthreads();
    }

#pragma unroll
    for (int n = 0; n < 4; ++n) {
        const int grow = row0 + n * 16 + lrow;
        if (grow >= M) continue;
#pragma unroll
        for (int m = 0; m < 2; ++m) {
            const int gcol = w * 32 + m * 16 + slot * 4;
            f32x4 bv = *(const f32x4*)(fcb + gcol);
            f32x4 o;
            o.x = acc[n][m][0] + bv.x;
            o.y = acc[n][m][1] + bv.y;
            o.z = acc[n][m][2] + bv.z;
            o.w = acc[n][m][3] + bv.w;
            *(f32x4*)(out + (size_t)grow * 128 + gcol) = o;
        }
    }
}

extern "C" void kernel_launch(void* const* d_in, const int* in_sizes, int n_in,
                              void* d_out, int out_size, void* d_ws, size_t ws_size,
                              hipStream_t stream) {
    const float* x_word = (const float*)d_in[0];
    const float* Wl  = (const float*)d_in[3];
    const float* bl  = (const float*)d_in[4];
    const float* Wr  = (const float*)d_in[5];
    const float* fcW = (const float*)d_in[6];
    const float* fcb = (const float*)d_in[7];
    const int* src = (const int*)d_in[8];
    const int* dst = (const int*)d_in[9];

    const int M = in_sizes[0] / 256;   // 200000
    const int E = in_sizes[8];         // 400000
    const int NB = (M + 1023) / 1024;

    char* ws = (char*)d_ws;
    size_t off = 0;
    auto alloc = [&](size_t bytes) {
        void* p = ws + off;
        off = (off + bytes + 255) & ~(size_t)255;
        return p;
    };
    int* cnt_i  = (int*)alloc((size_t)M * 4);
    int* rowptr = (int*)alloc((size_t)(M + 1) * 4);
    int* cursor = (int*)alloc((size_t)M * 4);
    int* eidx   = (int*)alloc((size_t)E * 4);
    int* bsum   = (int*)alloc((size_t)NB * 4);
    unsigned short* xb    = (unsigned short*)alloc((size_t)M * 256 * 2);
    unsigned short* meanb = (unsigned short*)alloc((size_t)M * 256 * 2);
    unsigned short* h     = (unsigned short*)alloc((size_t)M * 256 * 2);
    unsigned short* Wc1   = (unsigned short*)alloc(256 * 512 * 2);
    unsigned short* Wc2   = (unsigned short*)alloc(256 * 512 * 2);
    unsigned short* fcWb  = (unsigned short*)alloc(128 * 256 * 2);

    unsigned short* g = (unsigned short*)d_out;  // bf16 g staged inside d_out

    // CSR build
    hipMemsetAsync(cnt_i, 0, (size_t)M * 4, stream);
    k_hist<<<(E + 255) / 256, 256, 0, stream>>>(dst, cnt_i, E);
    k_bsum<<<NB, 256, 0, stream>>>(cnt_i, bsum, M);
    k_scanb<<<1, 64, 0, stream>>>(bsum, NB, rowptr, M, E);
    k_rowptr<<<NB, 256, 0, stream>>>(cnt_i, bsum, rowptr, cursor, M);
    k_place<<<(E + 255) / 256, 256, 0, stream>>>(src, dst, cursor, eidx, E);

    // weights + x -> bf16
    k_convw<<<1152, 256, 0, stream>>>(Wl, Wr, fcW, Wc1, Wc2, fcWb);
    k_convx<<<(M * 256 / 8 + 255) / 256, 256, 0, stream>>>(x_word, xb, M * 256 / 8);

    const int GB = (M + 63) / 64;

    // Layer 1
    k_gather_mean<<<(M + 3) / 4, 256, 0, stream>>>(xb, rowptr, eidx, meanb, M);
    k_sage_gemm<<<GB, 256, 0, stream>>>(meanb, xb, Wc1, bl, h, M);

    // Layer 2
    k_gather_mean<<<(M + 3) / 4, 256, 0, stream>>>(h, rowptr, eidx, meanb, M);
    k_sage_gemm<<<GB, 256, 0, stream>>>(meanb, h, Wc2, bl + 3 * 256, g, M);

    // fc head
    k_fc_gemm<<<GB, 256, 0, stream>>>(g, fcWb, fcb, (float*)d_out, M);
}

// Round 5
// 607.276 us; speedup vs baseline: 1.0924x; 1.0696x over previous
//
#include <hip/hip_runtime.h>

typedef __attribute__((ext_vector_type(8))) short bf16x8;
typedef __attribute__((ext_vector_type(4))) float f32x4;
typedef __attribute__((ext_vector_type(4))) unsigned short us4;

static __device__ __forceinline__ float bf2f(unsigned short u) {
    union { unsigned int i; float f; } cv; cv.i = ((unsigned int)u) << 16;
    return cv.f;
}
static __device__ __forceinline__ unsigned short f2bf(float f) {
    union { float f; unsigned int i; } cv; cv.f = f;
    unsigned int x = cv.i;
    unsigned int lsb = (x >> 16) & 1u;
    x += 0x7fffu + lsb;
    return (unsigned short)(x >> 16);
}

// async global->LDS, 16B per lane; LDS dest is wave-uniform base + lane*16
static __device__ __forceinline__ void gload16(const void* g, void* l) {
    __builtin_amdgcn_global_load_lds(
        (const __attribute__((address_space(1))) void*)g,
        (__attribute__((address_space(3))) void*)l, 16, 0, 0);
}

// ---------------- CSR build ----------------
__global__ __launch_bounds__(256) void k_hist(const int* __restrict__ dst,
                                              int* __restrict__ cnt, int E) {
    int i = blockIdx.x * 256 + threadIdx.x;
    if (i < E) atomicAdd(&cnt[dst[i]], 1);
}

__global__ __launch_bounds__(256) void k_bsum(const int* __restrict__ cnt,
                                              int* __restrict__ bsum, int M) {
    __shared__ int sm[256];
    int t = threadIdx.x;
    int base = blockIdx.x * 1024 + t * 4;
    int s = 0;
#pragma unroll
    for (int j = 0; j < 4; ++j) {
        int i = base + j;
        if (i < M) s += cnt[i];
    }
    sm[t] = s;
    __syncthreads();
    for (int off = 128; off; off >>= 1) {
        if (t < off) sm[t] += sm[t + off];
        __syncthreads();
    }
    if (t == 0) bsum[blockIdx.x] = sm[0];
}

__global__ void k_scanb(int* __restrict__ bsum, int NB,
                        int* __restrict__ rowptr, int M, int E) {
    if (threadIdx.x == 0 && blockIdx.x == 0) {
        int run = 0;
        for (int b = 0; b < NB; ++b) {
            int v = bsum[b];
            bsum[b] = run;
            run += v;
        }
        rowptr[M] = E;
    }
}

__global__ __launch_bounds__(256) void k_rowptr(const int* __restrict__ cnt,
                                                const int* __restrict__ bsum,
                                                int* __restrict__ rowptr,
                                                int* __restrict__ cursor, int M) {
    __shared__ int sm[256];
    int t = threadIdx.x;
    int base = blockIdx.x * 1024 + t * 4;
    int c[4];
    int ts = 0;
#pragma unroll
    for (int j = 0; j < 4; ++j) {
        int i = base + j;
        c[j] = (i < M) ? cnt[i] : 0;
        ts += c[j];
    }
    sm[t] = ts;
    __syncthreads();
    for (int off = 1; off < 256; off <<= 1) {
        int v = (t >= off) ? sm[t - off] : 0;
        __syncthreads();
        sm[t] += v;
        __syncthreads();
    }
    int ex = bsum[blockIdx.x] + sm[t] - ts;
#pragma unroll
    for (int j = 0; j < 4; ++j) {
        int i = base + j;
        if (i < M) {
            rowptr[i] = ex;
            cursor[i] = ex;
        }
        ex += c[j];
    }
}

__global__ __launch_bounds__(256) void k_place(const int* __restrict__ src,
                                               const int* __restrict__ dst,
                                               int* __restrict__ cursor,
                                               int* __restrict__ eidx, int E) {
    int i = blockIdx.x * 256 + threadIdx.x;
    if (i < E) {
        int slot = atomicAdd(&cursor[dst[i]], 1);
        eidx[slot] = src[i];
    }
}

// ---------------- f32 -> bf16 bulk convert ----------------
__global__ __launch_bounds__(256) void k_convx(const float* __restrict__ x,
                                               unsigned short* __restrict__ xb, int n8) {
    int i = blockIdx.x * 256 + threadIdx.x;
    if (i >= n8) return;
    const f32x4* p = (const f32x4*)(x + (size_t)i * 8);
    f32x4 u0 = p[0], u1 = p[1];
    union { bf16x8 v; unsigned short u[8]; } tmp;
    tmp.u[0] = f2bf(u0.x); tmp.u[1] = f2bf(u0.y);
    tmp.u[2] = f2bf(u0.z); tmp.u[3] = f2bf(u0.w);
    tmp.u[4] = f2bf(u1.x); tmp.u[5] = f2bf(u1.y);
    tmp.u[6] = f2bf(u1.z); tmp.u[7] = f2bf(u1.w);
    *(bf16x8*)(xb + (size_t)i * 8) = tmp.v;
}

// ---------------- pull aggregation: mean over neighbors (2-way ILP unroll) ----------------
__global__ __launch_bounds__(256) void k_gather_mean(const unsigned short* __restrict__ xsrc,
                                                     const int* __restrict__ rowptr,
                                                     const int* __restrict__ eidx,
                                                     unsigned short* __restrict__ mean, int M) {
    int r = blockIdx.x * 4 + (threadIdx.x >> 6);
    if (r >= M) return;
    int l = threadIdx.x & 63;
    int s0 = rowptr[r], s1 = rowptr[r + 1];
    float a0 = 0.f, a1 = 0.f, a2 = 0.f, a3 = 0.f;
    int e = s0;
    for (; e + 2 <= s1; e += 2) {
        int sA = eidx[e], sB = eidx[e + 1];
        us4 vA = *((const us4*)(xsrc + (size_t)sA * 256) + l);
        us4 vB = *((const us4*)(xsrc + (size_t)sB * 256) + l);
        a0 += bf2f(vA.x) + bf2f(vB.x);
        a1 += bf2f(vA.y) + bf2f(vB.y);
        a2 += bf2f(vA.z) + bf2f(vB.z);
        a3 += bf2f(vA.w) + bf2f(vB.w);
    }
    if (e < s1) {
        int sA = eidx[e];
        us4 vA = *((const us4*)(xsrc + (size_t)sA * 256) + l);
        a0 += bf2f(vA.x); a1 += bf2f(vA.y); a2 += bf2f(vA.z); a3 += bf2f(vA.w);
    }
    float rinv = (s1 > s0) ? 1.0f / (float)(s1 - s0) : 0.0f;
    us4 o;
    o.x = f2bf(a0 * rinv); o.y = f2bf(a1 * rinv);
    o.z = f2bf(a2 * rinv); o.w = f2bf(a3 * rinv);
    *((us4*)(mean + (size_t)r * 256) + l) = o;
}

// ---------------- weight conversion ----------------
__global__ __launch_bounds__(256) void k_convw(const float* __restrict__ Wl,
                                               const float* __restrict__ Wr,
                                               const float* __restrict__ fcW,
                                               unsigned short* __restrict__ Wc1,
                                               unsigned short* __restrict__ Wc2,
                                               unsigned short* __restrict__ fcWb) {
    int idx = blockIdx.x * 256 + threadIdx.x;
    if (idx < 2 * 256 * 512) {
        int layer = idx >> 17;
        int r = idx & ((1 << 17) - 1);
        int n = r >> 9;
        int k = r & 511;
        int base = layer * 3 * 256 * 256;
        float v = (k < 256) ? Wl[base + n * 256 + k] : Wr[base + n * 256 + (k - 256)];
        (layer ? Wc2 : Wc1)[n * 512 + k] = f2bf(v);
    } else {
        int i = idx - 2 * 256 * 512;
        if (i < 128 * 256) fcWb[i] = f2bf(fcW[i]);
    }
}

// ---------------- layer GEMM: out = relu([mean | xs] @ Wc^T + bias), bf16 out ----------------
// BM=128, BN=256(full), K=512, BK=32. 512 threads = 8 waves (2M x 4N), per-wave 64x64.
// Depth-3 counted-vmcnt pipeline: one raw s_barrier per step; vmcnt(3) never 0 in loop.
// Stage(s+2) targets the buffer retired at step s-1; the barrier is the WAR fence.
__global__ __launch_bounds__(512, 4) void k_sage_gemm(const unsigned short* __restrict__ meanb,
                                                      const unsigned short* __restrict__ xs,
                                                      const unsigned short* __restrict__ Wc,
                                                      const float* __restrict__ bias,
                                                      unsigned short* __restrict__ out, int M) {
    __shared__ __align__(16) unsigned short Asm[3][4096];   // 128 rows x 32 k, 16x32 frag-major subtiles
    __shared__ __align__(16) unsigned short Bsm[3][8192];   // 256 n   x 32 k
    const int t = threadIdx.x;
    const int w = t >> 6, l = t & 63;
    const int wr = w >> 2, wc = w & 3;
    const int lrow = l & 15, slot = l >> 4;
    const int row0 = blockIdx.x * 128;

    int a_row = row0 + w * 16 + lrow;
    if (a_row > M - 1) a_row = M - 1;
    const size_t a_base = (size_t)a_row * 256 + slot * 8;
    const size_t b_off0 = (size_t)(w * 16 + lrow) * 512 + slot * 8;
    const size_t b_off1 = (size_t)((w + 8) * 16 + lrow) * 512 + slot * 8;

    f32x4 acc[4][4];  // [act-row frag n][col frag m]
#pragma unroll
    for (int n = 0; n < 4; ++n)
#pragma unroll
        for (int m = 0; m < 4; ++m)
#pragma unroll
            for (int j = 0; j < 4; ++j) acc[n][m][j] = 0.0f;

    auto stage = [&](int bb, int step) {
        const int k0 = step * 32;
        const unsigned short* asrc = (k0 < 256) ? meanb + a_base + k0
                                                : xs + a_base + (k0 - 256);
        gload16(asrc, &Asm[bb][w * 512]);
        gload16(Wc + b_off0 + k0, &Bsm[bb][w * 512]);
        gload16(Wc + b_off1 + k0, &Bsm[bb][(w + 8) * 512]);
    };

    stage(0, 0);
    stage(1, 1);
#pragma unroll
    for (int s = 0; s < 16; ++s) {
        const int cur = s % 3;
        const int stb = (s + 2) % 3;
        // wait: tile s arrived (3 newest loads = tile s+1 still in flight)
        asm volatile("s_waitcnt vmcnt(3)" ::: "memory");
        __builtin_amdgcn_s_barrier();
        __builtin_amdgcn_sched_barrier(0);
        // issue tile s+2 immediately (lands >= global latency away; buffer retired at s-1)
        stage(stb, (s + 2 < 16) ? (s + 2) : 0);
        bf16x8 af[4], bf[4];
#pragma unroll
        for (int n = 0; n < 4; ++n)
            af[n] = *(const bf16x8*)(&Asm[cur][(wr * 4 + n) * 512 + l * 8]);
#pragma unroll
        for (int m = 0; m < 4; ++m)
            bf[m] = *(const bf16x8*)(&Bsm[cur][(wc * 4 + m) * 512 + l * 8]);
        __builtin_amdgcn_s_setprio(1);
#pragma unroll
        for (int n = 0; n < 4; ++n)
#pragma unroll
            for (int m = 0; m < 4; ++m)
                acc[n][m] = __builtin_amdgcn_mfma_f32_16x16x32_bf16(bf[m], af[n], acc[n][m], 0, 0, 0);
        __builtin_amdgcn_s_setprio(0);
        __builtin_amdgcn_sched_barrier(0);
        // ensure this step's ds_reads are architecturally complete before next barrier
        asm volatile("s_waitcnt lgkmcnt(0)" ::: "memory");
    }

    // epilogue: lane holds out[row0 + wr*64 + n*16 + lrow][wc*64 + m*16 + slot*4 + 0..3]
#pragma unroll
    for (int n = 0; n < 4; ++n) {
        const int grow = row0 + wr * 64 + n * 16 + lrow;
        if (grow >= M) continue;
#pragma unroll
        for (int m = 0; m < 4; ++m) {
            const int gcol = wc * 64 + m * 16 + slot * 4;
            f32x4 bv = *(const f32x4*)(bias + gcol);
            us4 o;
            o.x = f2bf(fmaxf(acc[n][m][0] + bv.x, 0.f));
            o.y = f2bf(fmaxf(acc[n][m][1] + bv.y, 0.f));
            o.z = f2bf(fmaxf(acc[n][m][2] + bv.z, 0.f));
            o.w = f2bf(fmaxf(acc[n][m][3] + bv.w, 0.f));
            *(us4*)(out + (size_t)grow * 256 + gcol) = o;
        }
    }
}

// ---------------- fc GEMM: out = g @ fcW^T + fcb, fp32 out; g aliases d_out ----------------
// BM=128, BN=128(full), K=256, BK=32. Same depth-3 counted pipeline; vmcnt(2).
__global__ __launch_bounds__(512, 6) void k_fc_gemm(const unsigned short* __restrict__ g,
                                                    const unsigned short* __restrict__ fcWb,
                                                    const float* __restrict__ fcb,
                                                    float* __restrict__ out, int M) {
    __shared__ __align__(16) unsigned short Asm[3][4096];   // 128 rows x 32 k
    __shared__ __align__(16) unsigned short Bsm[3][4096];   // 128 n   x 32 k
    const int t = threadIdx.x;
    const int w = t >> 6, l = t & 63;
    const int wr = w >> 2, wc = w & 3;
    const int lrow = l & 15, slot = l >> 4;
    const int row0 = blockIdx.x * 128;

    int a_row = row0 + w * 16 + lrow;
    if (a_row > M - 1) a_row = M - 1;
    const size_t a_base = (size_t)a_row * 256 + slot * 8;
    const size_t b_off = (size_t)(w * 16 + lrow) * 256 + slot * 8;

    f32x4 acc[4][2];
#pragma unroll
    for (int n = 0; n < 4; ++n)
#pragma unroll
        for (int m = 0; m < 2; ++m)
#pragma unroll
            for (int j = 0; j < 4; ++j) acc[n][m][j] = 0.0f;

    auto stage = [&](int bb, int step) {
        const int k0 = step * 32;
        gload16(g + a_base + k0, &Asm[bb][w * 512]);
        gload16(fcWb + b_off + k0, &Bsm[bb][w * 512]);
    };

    stage(0, 0);
    stage(1, 1);
#pragma unroll
    for (int s = 0; s < 8; ++s) {
        const int cur = s % 3;
        const int stb = (s + 2) % 3;
        asm volatile("s_waitcnt vmcnt(2)" ::: "memory");
        __builtin_amdgcn_s_barrier();
        __builtin_amdgcn_sched_barrier(0);
        stage(stb, (s + 2 < 8) ? (s + 2) : 0);
        bf16x8 af[4], bf[2];
#pragma unroll
        for (int n = 0; n < 4; ++n)
            af[n] = *(const bf16x8*)(&Asm[cur][(wr * 4 + n) * 512 + l * 8]);
#pragma unroll
        for (int m = 0; m < 2; ++m)
            bf[m] = *(const bf16x8*)(&Bsm[cur][(wc * 2 + m) * 512 + l * 8]);
        __builtin_amdgcn_s_setprio(1);
#pragma unroll
        for (int n = 0; n < 4; ++n)
#pragma unroll
            for (int m = 0; m < 2; ++m)
                acc[n][m] = __builtin_amdgcn_mfma_f32_16x16x32_bf16(bf[m], af[n], acc[n][m], 0, 0, 0);
        __builtin_amdgcn_s_setprio(0);
        __builtin_amdgcn_sched_barrier(0);
        asm volatile("s_waitcnt lgkmcnt(0)" ::: "memory");
    }

#pragma unroll
    for (int n = 0; n < 4; ++n) {
        const int grow = row0 + wr * 64 + n * 16 + lrow;
        if (grow >= M) continue;
#pragma unroll
        for (int m = 0; m < 2; ++m) {
            const int gcol = wc * 32 + m * 16 + slot * 4;
            f32x4 bv = *(const f32x4*)(fcb + gcol);
            f32x4 o;
            o.x = acc[n][m][0] + bv.x;
            o.y = acc[n][m][1] + bv.y;
            o.z = acc[n][m][2] + bv.z;
            o.w = acc[n][m][3] + bv.w;
            *(f32x4*)(out + (size_t)grow * 128 + gcol) = o;
        }
    }
}

extern "C" void kernel_launch(void* const* d_in, const int* in_sizes, int n_in,
                              void* d_out, int out_size, void* d_ws, size_t ws_size,
                              hipStream_t stream) {
    const float* x_word = (const float*)d_in[0];
    const float* Wl  = (const float*)d_in[3];
    const float* bl  = (const float*)d_in[4];
    const float* Wr  = (const float*)d_in[5];
    const float* fcW = (const float*)d_in[6];
    const float* fcb = (const float*)d_in[7];
    const int* src = (const int*)d_in[8];
    const int* dst = (const int*)d_in[9];

    const int M = in_sizes[0] / 256;   // 200000
    const int E = in_sizes[8];         // 400000
    const int NB = (M + 1023) / 1024;

    char* ws = (char*)d_ws;
    size_t off = 0;
    auto alloc = [&](size_t bytes) {
        void* p = ws + off;
        off = (off + bytes + 255) & ~(size_t)255;
        return p;
    };
    int* cnt_i  = (int*)alloc((size_t)M * 4);
    int* rowptr = (int*)alloc((size_t)(M + 1) * 4);
    int* cursor = (int*)alloc((size_t)M * 4);
    int* eidx   = (int*)alloc((size_t)E * 4);
    int* bsum   = (int*)alloc((size_t)NB * 4);
    unsigned short* xb    = (unsigned short*)alloc((size_t)M * 256 * 2);
    unsigned short* meanb = (unsigned short*)alloc((size_t)M * 256 * 2);
    unsigned short* h     = (unsigned short*)alloc((size_t)M * 256 * 2);
    unsigned short* Wc1   = (unsigned short*)alloc(256 * 512 * 2);
    unsigned short* Wc2   = (unsigned short*)alloc(256 * 512 * 2);
    unsigned short* fcWb  = (unsigned short*)alloc(128 * 256 * 2);

    unsigned short* g = (unsigned short*)d_out;  // bf16 g staged inside d_out

    // CSR build
    hipMemsetAsync(cnt_i, 0, (size_t)M * 4, stream);
    k_hist<<<(E + 255) / 256, 256, 0, stream>>>(dst, cnt_i, E);
    k_bsum<<<NB, 256, 0, stream>>>(cnt_i, bsum, M);
    k_scanb<<<1, 64, 0, stream>>>(bsum, NB, rowptr, M, E);
    k_rowptr<<<NB, 256, 0, stream>>>(cnt_i, bsum, rowptr, cursor, M);
    k_place<<<(E + 255) / 256, 256, 0, stream>>>(src, dst, cursor, eidx, E);

    // weights + x -> bf16
    k_convw<<<1152, 256, 0, stream>>>(Wl, Wr, fcW, Wc1, Wc2, fcWb);
    k_convx<<<(M * 256 / 8 + 255) / 256, 256, 0, stream>>>(x_word, xb, M * 256 / 8);

    const int GB = (M + 127) / 128;

    // Layer 1
    k_gather_mean<<<(M + 3) / 4, 256, 0, stream>>>(xb, rowptr, eidx, meanb, M);
    k_sage_gemm<<<GB, 512, 0, stream>>>(meanb, xb, Wc1, bl, h, M);

    // Layer 2
    k_gather_mean<<<(M + 3) / 4, 256, 0, stream>>>(h, rowptr, eidx, meanb, M);
    k_sage_gemm<<<GB, 512, 0, stream>>>(meanb, h, Wc2, bl + 3 * 256, g, M);

    // fc head
    k_fc_gemm<<<GB, 512, 0, stream>>>(g, fcWb, fcb, (float*)d_out, M);
}